// Round 8
// baseline (248.376 us; speedup 1.0000x reference)
//
#include <hip/hip_runtime.h>

// ---------------------------------------------------------------------------
// SelfAttentionPairDim2: B=4, N=256, M=256, D=64. Output [4,256,256,64].
// One workgroup (4 waves) per (b,i); fused MFMA pipeline:
//   QKV proj -> S=relu(K Q^T/8) -> rownorm -> P V -> out proj -> +x -> LN
//
// R8: attribution round. R7 bundled two levers; counters show the ct-unroll
// was ~neutral and the hot-kernel regression (147->174us) tracked
// FETCH_SIZE 38.5->62MB (+23.5MB @ 750GB/s = +31us): the R6 companion
// dispatch had been keeping X partially L3-resident, and single-dispatch
// lost that warmth. This round:
//  1. ct loop back to unroll 1 (R6's verified-fast phase 2).
//  2. Deliberate L3 warmth: warmx prefetch kernel (no LDS, grid-stride
//     uint4 reads of X, asm sink vs DCE; ~13us) before the main kernel.
//  3. Host-side dtype dispatch kept (saved 33us launch overhead).
// Frozen: 256 thr / 4 waves / 1 block/CU (R1/R2/R3/R5: any >1 wave/SIMD
// config fails O(1), mechanism unknown). R6 kept: swapped QK^T, in-register
// P fragment, 9 barriers/block.
// ---------------------------------------------------------------------------

using bh8   = __attribute__((ext_vector_type(8))) short;
using f32x4 = __attribute__((ext_vector_type(4))) float;

#define MFMA(a, b, c) __builtin_amdgcn_mfma_f32_16x16x32_bf16((a), (b), (c), 0, 0, 0)

#define SQ_STRIDE  72   // elements; 144 B rows (16B aligned)
#define SVT_STRIDE 264  // elements; 528 B rows (16B aligned)
#define SC_STRIDE  72
#define SY_STRIDE  72
#define STG_ELTS   (16 * SC_STRIDE)  // 1152
#define LDS_BYTES  ((256 * SQ_STRIDE * 2 + 64 * SVT_STRIDE + 4 * STG_ELTS) * 2)  // 116736 B

__device__ __forceinline__ float bf2f(unsigned short u) {
  union { unsigned int i; float f; } x;
  x.i = ((unsigned int)u) << 16;
  return x.f;
}
__device__ __forceinline__ unsigned short f2bf(float f) {
  union { float f; unsigned int i; } x;
  x.f = f;
  unsigned int u = x.i + 0x7FFFu + ((x.i >> 16) & 1u);  // RNE
  return (unsigned short)(u >> 16);
}
__device__ __forceinline__ int pkbf(float lo, float hi) {
  return (int)(((unsigned int)f2bf(hi) << 16) | (unsigned int)f2bf(lo));
}

template <int FP32>
__device__ __forceinline__ bh8 g_load8(const void* base, size_t idx) {
  if constexpr (FP32) {
    const float* p = (const float*)base + idx;
    float4 a = *(const float4*)p;
    float4 b = *(const float4*)(p + 4);
    bh8 r;
    r[0] = (short)f2bf(a.x); r[1] = (short)f2bf(a.y);
    r[2] = (short)f2bf(a.z); r[3] = (short)f2bf(a.w);
    r[4] = (short)f2bf(b.x); r[5] = (short)f2bf(b.y);
    r[6] = (short)f2bf(b.z); r[7] = (short)f2bf(b.w);
    return r;
  } else {
    return *(const bh8*)((const unsigned short*)base + idx);
  }
}
template <int FP32>
__device__ __forceinline__ float g_loadf(const void* base, size_t idx) {
  if constexpr (FP32) return ((const float*)base)[idx];
  else return bf2f(((const unsigned short*)base)[idx]);
}

// L3 prefetch: pull X into the cache hierarchy ahead of the main kernel.
// Read-only, no LDS (full occupancy), asm sink prevents DCE.
__global__ __launch_bounds__(256) void warmx(const void* __restrict__ Xv,
                                             long long n16) {
  const uint4* p = (const uint4*)Xv;
  long long i = (long long)blockIdx.x * 256 + threadIdx.x;
  const long long stride = (long long)gridDim.x * 256;
  unsigned a = 0, b = 0, c = 0, d = 0;
  for (; i < n16; i += stride) {
    uint4 v = p[i];
    a ^= v.x; b ^= v.y; c ^= v.z; d ^= v.w;
  }
  asm volatile("" :: "v"(a), "v"(b), "v"(c), "v"(d));
}

template <int FP32>
__global__ __launch_bounds__(256, 1) void pairattn(
    const void* __restrict__ Xv,
    const void* __restrict__ Wqv, const void* __restrict__ bqv,
    const void* __restrict__ Wkv, const void* __restrict__ bkv,
    const void* __restrict__ Wvv, const void* __restrict__ bvv,
    const void* __restrict__ Wov, const void* __restrict__ bov,
    const void* __restrict__ lngv, const void* __restrict__ lnbv,
    void* __restrict__ Outv) {
  const int tid  = threadIdx.x;
  const int lane = tid & 63;

  // ---- dtype detection (block-uniform, deterministic; guard for the
  // dual-launch fallback path) ----
  {
    const unsigned short* xu = (const unsigned short*)Xv + (lane << 4);
    int huge = 0;
#pragma unroll
    for (int j = 0; j < 16; ++j) {
      unsigned e = ((unsigned)xu[j] >> 7) & 0xFFu;
      huge |= (e >= 0x90u) ? 1 : 0;
    }
    const bool isf32 = (__ballot(huge) != 0ULL);
    if (isf32 != (FP32 != 0)) return;  // uniform exit, before any barrier
  }

  extern __shared__ unsigned short sm[];
  unsigned short* sQ  = sm;                        // 256 x 72
  unsigned short* sK  = sQ + 256 * SQ_STRIDE;      // 256 x 72
  unsigned short* sVt = sK + 256 * SQ_STRIDE;      // 64 x 264 (V transposed)
  unsigned short* sSt = sVt + 64 * SVT_STRIDE;     // 4 x 1152 wave-private

  const int wv  = tid >> 6;
  const int q4  = lane >> 4;
  const int l16 = lane & 15;
  const int m0w = wv << 6;
  const size_t xoff = (size_t)blockIdx.x * 16384;
  unsigned short* stg = sSt + wv * STG_ELTS;

  // ---------------- Phase 1: Q,K projections + V^T projection ---------------
  // (R0 verbatim)
#pragma unroll
  for (int p = 0; p < 2; ++p) {
    const void* W    = p ? Wkv : Wqv;
    const void* bias = p ? bkv : bqv;
    unsigned short* dst = p ? sK : sQ;
    bh8 wf[4][2];
    float bsf[4];
#pragma unroll
    for (int nt = 0; nt < 4; ++nt) {
      wf[nt][0] = g_load8<FP32>(W, (16 * nt + l16) * 64 + 8 * q4);
      wf[nt][1] = g_load8<FP32>(W, (16 * nt + l16) * 64 + 8 * q4 + 32);
      bsf[nt]   = g_loadf<FP32>(bias, 16 * nt + l16);
    }
#pragma unroll
    for (int mt = 0; mt < 4; ++mt) {
      const size_t xr = xoff + (size_t)(m0w + 16 * mt + l16) * 64 + 8 * q4;
      bh8 xf0 = g_load8<FP32>(Xv, xr);
      bh8 xf1 = g_load8<FP32>(Xv, xr + 32);
#pragma unroll
      for (int nt = 0; nt < 4; ++nt) {
        f32x4 acc = {0.f, 0.f, 0.f, 0.f};
        acc = MFMA(xf0, wf[nt][0], acc);
        acc = MFMA(xf1, wf[nt][1], acc);
#pragma unroll
        for (int r = 0; r < 4; ++r)
          dst[(m0w + 16 * mt + 4 * q4 + r) * SQ_STRIDE + 16 * nt + l16] =
              f2bf(acc[r] + bsf[nt]);
      }
    }
  }
  {
    bh8 wf[4][2];
    float bvf[4][4];
#pragma unroll
    for (int dt = 0; dt < 4; ++dt) {
      wf[dt][0] = g_load8<FP32>(Wvv, (16 * dt + l16) * 64 + 8 * q4);
      wf[dt][1] = g_load8<FP32>(Wvv, (16 * dt + l16) * 64 + 8 * q4 + 32);
#pragma unroll
      for (int r = 0; r < 4; ++r)
        bvf[dt][r] = g_loadf<FP32>(bvv, 16 * dt + 4 * q4 + r);
    }
#pragma unroll
    for (int mt = 0; mt < 4; ++mt) {
      const size_t xr = xoff + (size_t)(m0w + 16 * mt + l16) * 64 + 8 * q4;
      bh8 xf0 = g_load8<FP32>(Xv, xr);
      bh8 xf1 = g_load8<FP32>(Xv, xr + 32);
#pragma unroll
      for (int dt = 0; dt < 4; ++dt) {
        f32x4 acc = {0.f, 0.f, 0.f, 0.f};
        acc = MFMA(wf[dt][0], xf0, acc);
        acc = MFMA(wf[dt][1], xf1, acc);
#pragma unroll
        for (int r = 0; r < 4; ++r)
          sVt[(16 * dt + 4 * q4 + r) * SVT_STRIDE + m0w + 16 * mt + l16] =
              f2bf(acc[r] + bvf[dt][r]);
      }
    }
  }
  __syncthreads();  // sQ/sK/sVt valid block-wide

  float bof[4], gf[4], lbf[4];
#pragma unroll
  for (int nt = 0; nt < 4; ++nt) {
    const int col = 16 * nt + l16;
    bof[nt] = g_loadf<FP32>(bov, col);
    gf[nt]  = g_loadf<FP32>(lngv, col);
    lbf[nt] = g_loadf<FP32>(lnbv, col);
  }

  // Shuffle source lanes for the q4-axis fragment permutation:
  // target (q4,l16) dword j pulls from lane (2*(q4&1) + (j>>1), l16).
  const int srcA = ((lane & 16) << 1) | l16;  // q4' = 2*(q4&1)
  const int srcB = srcA + 16;                 // q4' = 2*(q4&1)+1
  const bool hsel = (lane & 32) != 0;         // h = q4>>1

  // ---------------- Phase 2: fused S -> P -> PV -> out -> LN ----------------
#pragma unroll 1
  for (int mt = 0; mt < 4; ++mt) {
    const int a0 = m0w + 16 * mt;
    const unsigned short* krow = sK + (a0 + l16) * SQ_STRIDE + 8 * q4;
    bh8 kf0 = *(const bh8*)(krow);
    bh8 kf1 = *(const bh8*)(krow + 32);
    f32x4 ctxa[4];
#pragma unroll
    for (int dt = 0; dt < 4; ++dt) ctxa[dt] = (f32x4){0.f, 0.f, 0.f, 0.f};
    float rs = 0.f;  // row-sum for row a = a0+l16 (lane-local partial)

#pragma unroll 1
    for (int ct = 0; ct < 8; ++ct) {
      // Swapped QK^T: s[r] = S[c0+4*q4+r][a0+l16]
      int ph0[2], ph1[2];
#pragma unroll
      for (int h = 0; h < 2; ++h) {
        const int c0 = 32 * ct + 16 * h;
        const unsigned short* qrow = sQ + (c0 + l16) * SQ_STRIDE + 8 * q4;
        bh8 qf0 = *(const bh8*)(qrow);
        bh8 qf1 = *(const bh8*)(qrow + 32);
        f32x4 s = {0.f, 0.f, 0.f, 0.f};
        s = MFMA(qf0, kf0, s);
        s = MFMA(qf1, kf1, s);
        float v0 = fmaxf(s[0] * 0.125f, 0.f);
        float v1 = fmaxf(s[1] * 0.125f, 0.f);
        float v2 = fmaxf(s[2] * 0.125f, 0.f);
        float v3 = fmaxf(s[3] * 0.125f, 0.f);
        rs += (v0 + v1) + (v2 + v3);
        if (h == 0) { ph0[0] = pkbf(v0, v1); ph0[1] = pkbf(v2, v3); }
        else        { ph1[0] = pkbf(v0, v1); ph1[1] = pkbf(v2, v3); }
      }
      // Build PV B-fragment in-register (no LDS, no barrier):
      // pf element s (k = 8*q4+s) = P[c-rel = 8*q4+s][a = l16].
      union { int d[4]; bh8 v; } pfu;
#pragma unroll
      for (int j = 0; j < 4; ++j) {
        const int srcl = (j < 2) ? srcA : srcB;
        int t0, t1;
        if ((j & 1) == 0) { t0 = __shfl(ph0[0], srcl); t1 = __shfl(ph1[0], srcl); }
        else              { t0 = __shfl(ph0[1], srcl); t1 = __shfl(ph1[1], srcl); }
        pfu.d[j] = hsel ? t1 : t0;
      }
#pragma unroll
      for (int dt = 0; dt < 4; ++dt) {
        bh8 vf = *(const bh8*)(sVt + (16 * dt + l16) * SVT_STRIDE + 32 * ct + 8 * q4);
        ctxa[dt] = MFMA(vf, pfu.v, ctxa[dt]);  // ctx^T[d][a]
      }
    }

    // denom = sum_c relu + M*1e-12 (reference adds 1e-12 inside the sum)
    rs += __shfl_xor(rs, 16);
    rs += __shfl_xor(rs, 32);
    const float inv = 1.f / (rs + 2.56e-10f);

    // ctx^T -> stg (row = a-rel = l16, col = d), then read back as R0 did.
#pragma unroll
    for (int dt = 0; dt < 4; ++dt)
#pragma unroll
      for (int r = 0; r < 4; ++r)
        stg[l16 * SC_STRIDE + 16 * dt + 4 * q4 + r] = f2bf(ctxa[dt][r] * inv);
    __syncthreads();  // insurance: ctx stage write -> read
    const unsigned short* crow = stg + l16 * SC_STRIDE + 8 * q4;
    bh8 cf0 = *(const bh8*)(crow);
    bh8 cf1 = *(const bh8*)(crow + 32);

    float yv[4][4];
    float s1[4] = {0.f, 0.f, 0.f, 0.f};
    float s2[4] = {0.f, 0.f, 0.f, 0.f};
#pragma unroll
    for (int nt = 0; nt < 4; ++nt) {
      bh8 wo0 = g_load8<FP32>(Wov, (16 * nt + l16) * 64 + 8 * q4);
      bh8 wo1 = g_load8<FP32>(Wov, (16 * nt + l16) * 64 + 8 * q4 + 32);
      f32x4 o = {0.f, 0.f, 0.f, 0.f};
      o = MFMA(cf0, wo0, o);
      o = MFMA(cf1, wo1, o);
#pragma unroll
      for (int r = 0; r < 4; ++r) {
        float y = o[r] + bof[nt] +
                  g_loadf<FP32>(Xv, xoff + (size_t)(a0 + 4 * q4 + r) * 64 + 16 * nt + l16);
        yv[nt][r] = y;
        s1[r] += y;
        s2[r] += y * y;
      }
    }
#pragma unroll
    for (int r = 0; r < 4; ++r) {
      s1[r] += __shfl_xor(s1[r], 1);
      s1[r] += __shfl_xor(s1[r], 2);
      s1[r] += __shfl_xor(s1[r], 4);
      s1[r] += __shfl_xor(s1[r], 8);
      s2[r] += __shfl_xor(s2[r], 1);
      s2[r] += __shfl_xor(s2[r], 2);
      s2[r] += __shfl_xor(s2[r], 4);
      s2[r] += __shfl_xor(s2[r], 8);
      const float mu   = s1[r] * 0.015625f;
      const float var  = s2[r] * 0.015625f - mu * mu;
      const float rstd = rsqrtf(var + 1e-5f);
      if constexpr (FP32) {
        float* Outf = (float*)Outv;
#pragma unroll
        for (int nt = 0; nt < 4; ++nt)
          Outf[xoff + (size_t)(a0 + 4 * q4 + r) * 64 + 16 * nt + l16] =
              (yv[nt][r] - mu) * rstd * gf[nt] + lbf[nt];
      } else {
#pragma unroll
        for (int nt = 0; nt < 4; ++nt)
          stg[(4 * q4 + r) * SY_STRIDE + 16 * nt + l16] =
              f2bf((yv[nt][r] - mu) * rstd * gf[nt] + lbf[nt]);
      }
    }
    if constexpr (!FP32) {
      __syncthreads();  // insurance: y stage write -> read
      const int row = lane >> 2, seg = lane & 3;
      const unsigned short* yr = stg + row * SY_STRIDE + seg * 8;
      uint4 u0 = *(const uint4*)(yr);
      uint4 u1 = *(const uint4*)(yr + 32);
      unsigned short* orow =
          (unsigned short*)Outv + xoff + (size_t)(a0 + row) * 64 + seg * 8;
      *(uint4*)(orow)      = u0;
      *(uint4*)(orow + 32) = u1;
    }
  }
}

extern "C" void kernel_launch(void* const* d_in, const int* in_sizes, int n_in,
                              void* d_out, int out_size, void* d_ws, size_t ws_size,
                              hipStream_t stream) {
  (void)n_in; (void)d_ws; (void)ws_size; (void)out_size;
  const void* X  = d_in[1];   // structure_matrix (d_in[0]=hidden_states unused)
  const void* Wq = d_in[2];  const void* bq = d_in[3];
  const void* Wk = d_in[4];  const void* bk = d_in[5];
  const void* Wv = d_in[6];  const void* bv = d_in[7];
  const void* Wo = d_in[8];  const void* bo = d_in[9];
  const void* lg = d_in[10]; const void* lb = d_in[11];

  // Host-side dtype dispatch: structure_matrix has 4*256*256*64 = 16777216
  // elements. If in_sizes[1] is a byte count it identifies the dtype and we
  // launch ONE kernel; any other value -> launch both (device sniff makes
  // the wrong one exit early, as before).
  const long long NELT = 16777216LL;
  const long long sz1  = (long long)in_sizes[1];
  bool want_bf16 = true, want_f32 = true;
  long long xbytes = 0;
  if (sz1 == NELT * 2) { want_f32 = false; xbytes = sz1; }       // bf16
  else if (sz1 == NELT * 4) { want_bf16 = false; xbytes = sz1; } // fp32

  // L3 prefetch of X ahead of the main kernel (only when dtype known).
  if (xbytes > 0)
    warmx<<<2048, 256, 0, stream>>>(X, xbytes >> 4);

  auto k0 = pairattn<0>;  // bf16 inputs/outputs
  auto k1 = pairattn<1>;  // fp32 inputs/outputs
  if (want_bf16) {
    hipFuncSetAttribute((const void*)k0, hipFuncAttributeMaxDynamicSharedMemorySize, LDS_BYTES);
    k0<<<1024, 256, LDS_BYTES, stream>>>(X, Wq, bq, Wk, bk, Wv, bv, Wo, bo, lg, lb, d_out);
  }
  if (want_f32) {
    hipFuncSetAttribute((const void*)k1, hipFuncAttributeMaxDynamicSharedMemorySize, LDS_BYTES);
    k1<<<1024, 256, LDS_BYTES, stream>>>(X, Wq, bq, Wk, bk, Wv, bv, Wo, bo, lg, lb, d_out);
  }
}

// Round 9
// 248.340 us; speedup vs baseline: 1.0001x; 1.0001x over previous
//
#include <hip/hip_runtime.h>

// ---------------------------------------------------------------------------
// SelfAttentionPairDim2: B=4, N=256, M=256, D=64. Output [4,256,256,64].
// One workgroup (4 waves) per (b,i); fused MFMA pipeline:
//   QKV proj -> S=relu(K Q^T/8) -> rownorm -> P V -> out proj -> +x -> LN
//
// R9: recombination of verified-best pieces (single variable vs R8: warmx
// removed). Attribution ledger:
//  * unroll2 on ct loop = +27us hot regression (R7 174 vs R6/R8 147) -> out.
//  * warmx prefetch = 0 on hot kernel (R8 147us, FETCH unchanged 62MB),
//    −35us on metric overhead -> out.
//  * duration INSENSITIVE to FETCH_SIZE (R6 38.5MB@147us vs R8 62MB@147us)
//    -> latency-bound, not BW-bound; cache-warmth levers are dead.
//  * single-dispatch host path = 66us overhead vs 100us dual -> keep.
// Frozen: 256 thr / 4 waves / 1 block/CU (R1/R2/R3/R5: any >1 wave/SIMD
// config fails O(1), mechanism unknown). Kept from R6: swapped QK^T
// (lane-local row-sum), in-register P fragment via 8 shfl, 9 barriers/blk.
// ---------------------------------------------------------------------------

using bh8   = __attribute__((ext_vector_type(8))) short;
using f32x4 = __attribute__((ext_vector_type(4))) float;

#define MFMA(a, b, c) __builtin_amdgcn_mfma_f32_16x16x32_bf16((a), (b), (c), 0, 0, 0)

#define SQ_STRIDE  72   // elements; 144 B rows (16B aligned)
#define SVT_STRIDE 264  // elements; 528 B rows (16B aligned)
#define SC_STRIDE  72
#define SY_STRIDE  72
#define STG_ELTS   (16 * SC_STRIDE)  // 1152
#define LDS_BYTES  ((256 * SQ_STRIDE * 2 + 64 * SVT_STRIDE + 4 * STG_ELTS) * 2)  // 116736 B

__device__ __forceinline__ float bf2f(unsigned short u) {
  union { unsigned int i; float f; } x;
  x.i = ((unsigned int)u) << 16;
  return x.f;
}
__device__ __forceinline__ unsigned short f2bf(float f) {
  union { float f; unsigned int i; } x;
  x.f = f;
  unsigned int u = x.i + 0x7FFFu + ((x.i >> 16) & 1u);  // RNE
  return (unsigned short)(u >> 16);
}
__device__ __forceinline__ int pkbf(float lo, float hi) {
  return (int)(((unsigned int)f2bf(hi) << 16) | (unsigned int)f2bf(lo));
}

template <int FP32>
__device__ __forceinline__ bh8 g_load8(const void* base, size_t idx) {
  if constexpr (FP32) {
    const float* p = (const float*)base + idx;
    float4 a = *(const float4*)p;
    float4 b = *(const float4*)(p + 4);
    bh8 r;
    r[0] = (short)f2bf(a.x); r[1] = (short)f2bf(a.y);
    r[2] = (short)f2bf(a.z); r[3] = (short)f2bf(a.w);
    r[4] = (short)f2bf(b.x); r[5] = (short)f2bf(b.y);
    r[6] = (short)f2bf(b.z); r[7] = (short)f2bf(b.w);
    return r;
  } else {
    return *(const bh8*)((const unsigned short*)base + idx);
  }
}
template <int FP32>
__device__ __forceinline__ float g_loadf(const void* base, size_t idx) {
  if constexpr (FP32) return ((const float*)base)[idx];
  else return bf2f(((const unsigned short*)base)[idx]);
}

template <int FP32>
__global__ __launch_bounds__(256, 1) void pairattn(
    const void* __restrict__ Xv,
    const void* __restrict__ Wqv, const void* __restrict__ bqv,
    const void* __restrict__ Wkv, const void* __restrict__ bkv,
    const void* __restrict__ Wvv, const void* __restrict__ bvv,
    const void* __restrict__ Wov, const void* __restrict__ bov,
    const void* __restrict__ lngv, const void* __restrict__ lnbv,
    void* __restrict__ Outv) {
  const int tid  = threadIdx.x;
  const int lane = tid & 63;

  // ---- dtype detection (block-uniform, deterministic; guard for the
  // dual-launch fallback path) ----
  {
    const unsigned short* xu = (const unsigned short*)Xv + (lane << 4);
    int huge = 0;
#pragma unroll
    for (int j = 0; j < 16; ++j) {
      unsigned e = ((unsigned)xu[j] >> 7) & 0xFFu;
      huge |= (e >= 0x90u) ? 1 : 0;
    }
    const bool isf32 = (__ballot(huge) != 0ULL);
    if (isf32 != (FP32 != 0)) return;  // uniform exit, before any barrier
  }

  extern __shared__ unsigned short sm[];
  unsigned short* sQ  = sm;                        // 256 x 72
  unsigned short* sK  = sQ + 256 * SQ_STRIDE;      // 256 x 72
  unsigned short* sVt = sK + 256 * SQ_STRIDE;      // 64 x 264 (V transposed)
  unsigned short* sSt = sVt + 64 * SVT_STRIDE;     // 4 x 1152 wave-private

  const int wv  = tid >> 6;
  const int q4  = lane >> 4;
  const int l16 = lane & 15;
  const int m0w = wv << 6;
  const size_t xoff = (size_t)blockIdx.x * 16384;
  unsigned short* stg = sSt + wv * STG_ELTS;

  // ---------------- Phase 1: Q,K projections + V^T projection ---------------
  // (R0 verbatim)
#pragma unroll
  for (int p = 0; p < 2; ++p) {
    const void* W    = p ? Wkv : Wqv;
    const void* bias = p ? bkv : bqv;
    unsigned short* dst = p ? sK : sQ;
    bh8 wf[4][2];
    float bsf[4];
#pragma unroll
    for (int nt = 0; nt < 4; ++nt) {
      wf[nt][0] = g_load8<FP32>(W, (16 * nt + l16) * 64 + 8 * q4);
      wf[nt][1] = g_load8<FP32>(W, (16 * nt + l16) * 64 + 8 * q4 + 32);
      bsf[nt]   = g_loadf<FP32>(bias, 16 * nt + l16);
    }
#pragma unroll
    for (int mt = 0; mt < 4; ++mt) {
      const size_t xr = xoff + (size_t)(m0w + 16 * mt + l16) * 64 + 8 * q4;
      bh8 xf0 = g_load8<FP32>(Xv, xr);
      bh8 xf1 = g_load8<FP32>(Xv, xr + 32);
#pragma unroll
      for (int nt = 0; nt < 4; ++nt) {
        f32x4 acc = {0.f, 0.f, 0.f, 0.f};
        acc = MFMA(xf0, wf[nt][0], acc);
        acc = MFMA(xf1, wf[nt][1], acc);
#pragma unroll
        for (int r = 0; r < 4; ++r)
          dst[(m0w + 16 * mt + 4 * q4 + r) * SQ_STRIDE + 16 * nt + l16] =
              f2bf(acc[r] + bsf[nt]);
      }
    }
  }
  {
    bh8 wf[4][2];
    float bvf[4][4];
#pragma unroll
    for (int dt = 0; dt < 4; ++dt) {
      wf[dt][0] = g_load8<FP32>(Wvv, (16 * dt + l16) * 64 + 8 * q4);
      wf[dt][1] = g_load8<FP32>(Wvv, (16 * dt + l16) * 64 + 8 * q4 + 32);
#pragma unroll
      for (int r = 0; r < 4; ++r)
        bvf[dt][r] = g_loadf<FP32>(bvv, 16 * dt + 4 * q4 + r);
    }
#pragma unroll
    for (int mt = 0; mt < 4; ++mt) {
      const size_t xr = xoff + (size_t)(m0w + 16 * mt + l16) * 64 + 8 * q4;
      bh8 xf0 = g_load8<FP32>(Xv, xr);
      bh8 xf1 = g_load8<FP32>(Xv, xr + 32);
#pragma unroll
      for (int dt = 0; dt < 4; ++dt) {
        f32x4 acc = {0.f, 0.f, 0.f, 0.f};
        acc = MFMA(wf[dt][0], xf0, acc);
        acc = MFMA(wf[dt][1], xf1, acc);
#pragma unroll
        for (int r = 0; r < 4; ++r)
          sVt[(16 * dt + 4 * q4 + r) * SVT_STRIDE + m0w + 16 * mt + l16] =
              f2bf(acc[r] + bvf[dt][r]);
      }
    }
  }
  __syncthreads();  // sQ/sK/sVt valid block-wide

  float bof[4], gf[4], lbf[4];
#pragma unroll
  for (int nt = 0; nt < 4; ++nt) {
    const int col = 16 * nt + l16;
    bof[nt] = g_loadf<FP32>(bov, col);
    gf[nt]  = g_loadf<FP32>(lngv, col);
    lbf[nt] = g_loadf<FP32>(lnbv, col);
  }

  // Shuffle source lanes for the q4-axis fragment permutation:
  // target (q4,l16) dword j pulls from lane (2*(q4&1) + (j>>1), l16).
  const int srcA = ((lane & 16) << 1) | l16;  // q4' = 2*(q4&1)
  const int srcB = srcA + 16;                 // q4' = 2*(q4&1)+1
  const bool hsel = (lane & 32) != 0;         // h = q4>>1

  // ---------------- Phase 2: fused S -> P -> PV -> out -> LN ----------------
#pragma unroll 1
  for (int mt = 0; mt < 4; ++mt) {
    const int a0 = m0w + 16 * mt;
    const unsigned short* krow = sK + (a0 + l16) * SQ_STRIDE + 8 * q4;
    bh8 kf0 = *(const bh8*)(krow);
    bh8 kf1 = *(const bh8*)(krow + 32);
    f32x4 ctxa[4];
#pragma unroll
    for (int dt = 0; dt < 4; ++dt) ctxa[dt] = (f32x4){0.f, 0.f, 0.f, 0.f};
    float rs = 0.f;  // row-sum for row a = a0+l16 (lane-local partial)

#pragma unroll 1
    for (int ct = 0; ct < 8; ++ct) {
      // Swapped QK^T: s[r] = S[c0+4*q4+r][a0+l16]
      int ph0[2], ph1[2];
#pragma unroll
      for (int h = 0; h < 2; ++h) {
        const int c0 = 32 * ct + 16 * h;
        const unsigned short* qrow = sQ + (c0 + l16) * SQ_STRIDE + 8 * q4;
        bh8 qf0 = *(const bh8*)(qrow);
        bh8 qf1 = *(const bh8*)(qrow + 32);
        f32x4 s = {0.f, 0.f, 0.f, 0.f};
        s = MFMA(qf0, kf0, s);
        s = MFMA(qf1, kf1, s);
        float v0 = fmaxf(s[0] * 0.125f, 0.f);
        float v1 = fmaxf(s[1] * 0.125f, 0.f);
        float v2 = fmaxf(s[2] * 0.125f, 0.f);
        float v3 = fmaxf(s[3] * 0.125f, 0.f);
        rs += (v0 + v1) + (v2 + v3);
        if (h == 0) { ph0[0] = pkbf(v0, v1); ph0[1] = pkbf(v2, v3); }
        else        { ph1[0] = pkbf(v0, v1); ph1[1] = pkbf(v2, v3); }
      }
      // Build PV B-fragment in-register (no LDS, no barrier):
      // pf element s (k = 8*q4+s) = P[c-rel = 8*q4+s][a = l16].
      union { int d[4]; bh8 v; } pfu;
#pragma unroll
      for (int j = 0; j < 4; ++j) {
        const int srcl = (j < 2) ? srcA : srcB;
        int t0, t1;
        if ((j & 1) == 0) { t0 = __shfl(ph0[0], srcl); t1 = __shfl(ph1[0], srcl); }
        else              { t0 = __shfl(ph0[1], srcl); t1 = __shfl(ph1[1], srcl); }
        pfu.d[j] = hsel ? t1 : t0;
      }
#pragma unroll
      for (int dt = 0; dt < 4; ++dt) {
        bh8 vf = *(const bh8*)(sVt + (16 * dt + l16) * SVT_STRIDE + 32 * ct + 8 * q4);
        ctxa[dt] = MFMA(vf, pfu.v, ctxa[dt]);  // ctx^T[d][a]
      }
    }

    // denom = sum_c relu + M*1e-12 (reference adds 1e-12 inside the sum)
    rs += __shfl_xor(rs, 16);
    rs += __shfl_xor(rs, 32);
    const float inv = 1.f / (rs + 2.56e-10f);

    // ctx^T -> stg (row = a-rel = l16, col = d), then read back as R0 did.
#pragma unroll
    for (int dt = 0; dt < 4; ++dt)
#pragma unroll
      for (int r = 0; r < 4; ++r)
        stg[l16 * SC_STRIDE + 16 * dt + 4 * q4 + r] = f2bf(ctxa[dt][r] * inv);
    __syncthreads();  // insurance: ctx stage write -> read
    const unsigned short* crow = stg + l16 * SC_STRIDE + 8 * q4;
    bh8 cf0 = *(const bh8*)(crow);
    bh8 cf1 = *(const bh8*)(crow + 32);

    float yv[4][4];
    float s1[4] = {0.f, 0.f, 0.f, 0.f};
    float s2[4] = {0.f, 0.f, 0.f, 0.f};
#pragma unroll
    for (int nt = 0; nt < 4; ++nt) {
      bh8 wo0 = g_load8<FP32>(Wov, (16 * nt + l16) * 64 + 8 * q4);
      bh8 wo1 = g_load8<FP32>(Wov, (16 * nt + l16) * 64 + 8 * q4 + 32);
      f32x4 o = {0.f, 0.f, 0.f, 0.f};
      o = MFMA(cf0, wo0, o);
      o = MFMA(cf1, wo1, o);
#pragma unroll
      for (int r = 0; r < 4; ++r) {
        float y = o[r] + bof[nt] +
                  g_loadf<FP32>(Xv, xoff + (size_t)(a0 + 4 * q4 + r) * 64 + 16 * nt + l16);
        yv[nt][r] = y;
        s1[r] += y;
        s2[r] += y * y;
      }
    }
#pragma unroll
    for (int r = 0; r < 4; ++r) {
      s1[r] += __shfl_xor(s1[r], 1);
      s1[r] += __shfl_xor(s1[r], 2);
      s1[r] += __shfl_xor(s1[r], 4);
      s1[r] += __shfl_xor(s1[r], 8);
      s2[r] += __shfl_xor(s2[r], 1);
      s2[r] += __shfl_xor(s2[r], 2);
      s2[r] += __shfl_xor(s2[r], 4);
      s2[r] += __shfl_xor(s2[r], 8);
      const float mu   = s1[r] * 0.015625f;
      const float var  = s2[r] * 0.015625f - mu * mu;
      const float rstd = rsqrtf(var + 1e-5f);
      if constexpr (FP32) {
        float* Outf = (float*)Outv;
#pragma unroll
        for (int nt = 0; nt < 4; ++nt)
          Outf[xoff + (size_t)(a0 + 4 * q4 + r) * 64 + 16 * nt + l16] =
              (yv[nt][r] - mu) * rstd * gf[nt] + lbf[nt];
      } else {
#pragma unroll
        for (int nt = 0; nt < 4; ++nt)
          stg[(4 * q4 + r) * SY_STRIDE + 16 * nt + l16] =
              f2bf((yv[nt][r] - mu) * rstd * gf[nt] + lbf[nt]);
      }
    }
    if constexpr (!FP32) {
      __syncthreads();  // insurance: y stage write -> read
      const int row = lane >> 2, seg = lane & 3;
      const unsigned short* yr = stg + row * SY_STRIDE + seg * 8;
      uint4 u0 = *(const uint4*)(yr);
      uint4 u1 = *(const uint4*)(yr + 32);
      unsigned short* orow =
          (unsigned short*)Outv + xoff + (size_t)(a0 + row) * 64 + seg * 8;
      *(uint4*)(orow)      = u0;
      *(uint4*)(orow + 32) = u1;
    }
  }
}

extern "C" void kernel_launch(void* const* d_in, const int* in_sizes, int n_in,
                              void* d_out, int out_size, void* d_ws, size_t ws_size,
                              hipStream_t stream) {
  (void)n_in; (void)d_ws; (void)ws_size; (void)out_size;
  const void* X  = d_in[1];   // structure_matrix (d_in[0]=hidden_states unused)
  const void* Wq = d_in[2];  const void* bq = d_in[3];
  const void* Wk = d_in[4];  const void* bk = d_in[5];
  const void* Wv = d_in[6];  const void* bv = d_in[7];
  const void* Wo = d_in[8];  const void* bo = d_in[9];
  const void* lg = d_in[10]; const void* lb = d_in[11];

  // Host-side dtype dispatch: structure_matrix has 4*256*256*64 = 16777216
  // elements. If in_sizes[1] is a byte count it identifies the dtype and we
  // launch ONE kernel; any other value -> launch both (device sniff makes
  // the wrong one exit early, as before).
  const long long NELT = 16777216LL;
  const long long sz1  = (long long)in_sizes[1];
  bool want_bf16 = true, want_f32 = true;
  if (sz1 == NELT * 2) want_f32 = false;        // bf16 bytes
  else if (sz1 == NELT * 4) want_bf16 = false;  // fp32 bytes

  auto k0 = pairattn<0>;  // bf16 inputs/outputs
  auto k1 = pairattn<1>;  // fp32 inputs/outputs
  if (want_bf16) {
    hipFuncSetAttribute((const void*)k0, hipFuncAttributeMaxDynamicSharedMemorySize, LDS_BYTES);
    k0<<<1024, 256, LDS_BYTES, stream>>>(X, Wq, bq, Wk, bk, Wv, bv, Wo, bo, lg, lb, d_out);
  }
  if (want_f32) {
    hipFuncSetAttribute((const void*)k1, hipFuncAttributeMaxDynamicSharedMemorySize, LDS_BYTES);
    k1<<<1024, 256, LDS_BYTES, stream>>>(X, Wq, bq, Wk, bk, Wv, bv, Wo, bo, lg, lb, d_out);
  }
}

// Round 10
// 233.961 us; speedup vs baseline: 1.0616x; 1.0615x over previous
//
#include <hip/hip_runtime.h>

// ---------------------------------------------------------------------------
// SelfAttentionPairDim2: B=4, N=256, M=256, D=64. Output [4,256,256,64].
// One workgroup (4 waves) per (b,i); fused MFMA pipeline:
//   QKV proj -> S=relu(K Q^T/8) -> rownorm -> P V -> out proj -> +x -> LN
//
// R10: serial-load-head elimination (VGPRs are the only abundant resource
// at 1 wave/SIMD). Ledger: rocprof dispatch durations have +-20% noise
// (R8 147us vs R9 180us, identical binary); trust the bench metric
// (R6 247 / R7 240 / R8-R9 248). Cache-warmth + unroll levers dead.
// This round (pure reordering of verified arithmetic, frozen geometry):
//  * Phase 1 merged: Wq/Wk/Wv + all biases preloaded ONCE (96+24 VGPR),
//    X tile loaded ONCE per mt (was 3x: Q, K, V passes each reloaded it,
//    each behind a serial weight-load head).
//  * Wo preloaded once before the phase-2 mt loop (was reloaded per mt:
//    32 global loads -> 8).
//  * Everything else R9 verbatim: swapped QK^T, in-register P fragment,
//    unroll-1 ct loop, 9 barriers/block, single-dispatch host path.
// Frozen: 256 thr / 4 waves / 1 block/CU (any >1 wave/SIMD config fails
// O(1), mechanism unknown -- R1/R2/R3/R5).
// ---------------------------------------------------------------------------

using bh8   = __attribute__((ext_vector_type(8))) short;
using f32x4 = __attribute__((ext_vector_type(4))) float;

#define MFMA(a, b, c) __builtin_amdgcn_mfma_f32_16x16x32_bf16((a), (b), (c), 0, 0, 0)

#define SQ_STRIDE  72   // elements; 144 B rows (16B aligned)
#define SVT_STRIDE 264  // elements; 528 B rows (16B aligned)
#define SC_STRIDE  72
#define SY_STRIDE  72
#define STG_ELTS   (16 * SC_STRIDE)  // 1152
#define LDS_BYTES  ((256 * SQ_STRIDE * 2 + 64 * SVT_STRIDE + 4 * STG_ELTS) * 2)  // 116736 B

__device__ __forceinline__ float bf2f(unsigned short u) {
  union { unsigned int i; float f; } x;
  x.i = ((unsigned int)u) << 16;
  return x.f;
}
__device__ __forceinline__ unsigned short f2bf(float f) {
  union { float f; unsigned int i; } x;
  x.f = f;
  unsigned int u = x.i + 0x7FFFu + ((x.i >> 16) & 1u);  // RNE
  return (unsigned short)(u >> 16);
}
__device__ __forceinline__ int pkbf(float lo, float hi) {
  return (int)(((unsigned int)f2bf(hi) << 16) | (unsigned int)f2bf(lo));
}

template <int FP32>
__device__ __forceinline__ bh8 g_load8(const void* base, size_t idx) {
  if constexpr (FP32) {
    const float* p = (const float*)base + idx;
    float4 a = *(const float4*)p;
    float4 b = *(const float4*)(p + 4);
    bh8 r;
    r[0] = (short)f2bf(a.x); r[1] = (short)f2bf(a.y);
    r[2] = (short)f2bf(a.z); r[3] = (short)f2bf(a.w);
    r[4] = (short)f2bf(b.x); r[5] = (short)f2bf(b.y);
    r[6] = (short)f2bf(b.z); r[7] = (short)f2bf(b.w);
    return r;
  } else {
    return *(const bh8*)((const unsigned short*)base + idx);
  }
}
template <int FP32>
__device__ __forceinline__ float g_loadf(const void* base, size_t idx) {
  if constexpr (FP32) return ((const float*)base)[idx];
  else return bf2f(((const unsigned short*)base)[idx]);
}

template <int FP32>
__global__ __launch_bounds__(256, 1) void pairattn(
    const void* __restrict__ Xv,
    const void* __restrict__ Wqv, const void* __restrict__ bqv,
    const void* __restrict__ Wkv, const void* __restrict__ bkv,
    const void* __restrict__ Wvv, const void* __restrict__ bvv,
    const void* __restrict__ Wov, const void* __restrict__ bov,
    const void* __restrict__ lngv, const void* __restrict__ lnbv,
    void* __restrict__ Outv) {
  const int tid  = threadIdx.x;
  const int lane = tid & 63;

  // ---- dtype detection (block-uniform, deterministic; guard for the
  // dual-launch fallback path) ----
  {
    const unsigned short* xu = (const unsigned short*)Xv + (lane << 4);
    int huge = 0;
#pragma unroll
    for (int j = 0; j < 16; ++j) {
      unsigned e = ((unsigned)xu[j] >> 7) & 0xFFu;
      huge |= (e >= 0x90u) ? 1 : 0;
    }
    const bool isf32 = (__ballot(huge) != 0ULL);
    if (isf32 != (FP32 != 0)) return;  // uniform exit, before any barrier
  }

  extern __shared__ unsigned short sm[];
  unsigned short* sQ  = sm;                        // 256 x 72
  unsigned short* sK  = sQ + 256 * SQ_STRIDE;      // 256 x 72
  unsigned short* sVt = sK + 256 * SQ_STRIDE;      // 64 x 264 (V transposed)
  unsigned short* sSt = sVt + 64 * SVT_STRIDE;     // 4 x 1152 wave-private

  const int wv  = tid >> 6;
  const int q4  = lane >> 4;
  const int l16 = lane & 15;
  const int m0w = wv << 6;
  const size_t xoff = (size_t)blockIdx.x * 16384;
  unsigned short* stg = sSt + wv * STG_ELTS;

  // ---------------- Phase 1 (merged): Q,K,V^T with one X load per mt -------
  // All weight fragments + biases preloaded once; identical MFMAs/stores to
  // the verified R0/R9 phase 1, just reordered so X is loaded once.
  {
    bh8 wq[4][2], wk[4][2], wvv[4][2];
    float bqf[4], bkf[4], bvf[4][4];
#pragma unroll
    for (int nt = 0; nt < 4; ++nt) {
      const int wrow = (16 * nt + l16) * 64 + 8 * q4;
      wq[nt][0]  = g_load8<FP32>(Wqv, wrow);
      wq[nt][1]  = g_load8<FP32>(Wqv, wrow + 32);
      wk[nt][0]  = g_load8<FP32>(Wkv, wrow);
      wk[nt][1]  = g_load8<FP32>(Wkv, wrow + 32);
      wvv[nt][0] = g_load8<FP32>(Wvv, wrow);
      wvv[nt][1] = g_load8<FP32>(Wvv, wrow + 32);
      bqf[nt]    = g_loadf<FP32>(bqv, 16 * nt + l16);
      bkf[nt]    = g_loadf<FP32>(bkv, 16 * nt + l16);
#pragma unroll
      for (int r = 0; r < 4; ++r)
        bvf[nt][r] = g_loadf<FP32>(bvv, 16 * nt + 4 * q4 + r);
    }
#pragma unroll
    for (int mt = 0; mt < 4; ++mt) {
      const size_t xr = xoff + (size_t)(m0w + 16 * mt + l16) * 64 + 8 * q4;
      bh8 xf0 = g_load8<FP32>(Xv, xr);
      bh8 xf1 = g_load8<FP32>(Xv, xr + 32);
      // Q projection -> sQ
#pragma unroll
      for (int nt = 0; nt < 4; ++nt) {
        f32x4 acc = {0.f, 0.f, 0.f, 0.f};
        acc = MFMA(xf0, wq[nt][0], acc);
        acc = MFMA(xf1, wq[nt][1], acc);
#pragma unroll
        for (int r = 0; r < 4; ++r)
          sQ[(m0w + 16 * mt + 4 * q4 + r) * SQ_STRIDE + 16 * nt + l16] =
              f2bf(acc[r] + bqf[nt]);
      }
      // K projection -> sK
#pragma unroll
      for (int nt = 0; nt < 4; ++nt) {
        f32x4 acc = {0.f, 0.f, 0.f, 0.f};
        acc = MFMA(xf0, wk[nt][0], acc);
        acc = MFMA(xf1, wk[nt][1], acc);
#pragma unroll
        for (int r = 0; r < 4; ++r)
          sK[(m0w + 16 * mt + 4 * q4 + r) * SQ_STRIDE + 16 * nt + l16] =
              f2bf(acc[r] + bkf[nt]);
      }
      // V^T projection -> sVt
#pragma unroll
      for (int dt = 0; dt < 4; ++dt) {
        f32x4 acc = {0.f, 0.f, 0.f, 0.f};
        acc = MFMA(wvv[dt][0], xf0, acc);
        acc = MFMA(wvv[dt][1], xf1, acc);
#pragma unroll
        for (int r = 0; r < 4; ++r)
          sVt[(16 * dt + 4 * q4 + r) * SVT_STRIDE + m0w + 16 * mt + l16] =
              f2bf(acc[r] + bvf[dt][r]);
      }
    }
  }
  __syncthreads();  // sQ/sK/sVt valid block-wide

  // Preload Wo fragments + output-stage constants once (was per-mt).
  bh8 wo[4][2];
  float bof[4], gf[4], lbf[4];
#pragma unroll
  for (int nt = 0; nt < 4; ++nt) {
    const int wrow = (16 * nt + l16) * 64 + 8 * q4;
    wo[nt][0] = g_load8<FP32>(Wov, wrow);
    wo[nt][1] = g_load8<FP32>(Wov, wrow + 32);
    const int col = 16 * nt + l16;
    bof[nt] = g_loadf<FP32>(bov, col);
    gf[nt]  = g_loadf<FP32>(lngv, col);
    lbf[nt] = g_loadf<FP32>(lnbv, col);
  }

  // Shuffle source lanes for the q4-axis fragment permutation:
  // target (q4,l16) dword j pulls from lane (2*(q4&1) + (j>>1), l16).
  const int srcA = ((lane & 16) << 1) | l16;  // q4' = 2*(q4&1)
  const int srcB = srcA + 16;                 // q4' = 2*(q4&1)+1
  const bool hsel = (lane & 32) != 0;         // h = q4>>1

  // ---------------- Phase 2: fused S -> P -> PV -> out -> LN ----------------
#pragma unroll 1
  for (int mt = 0; mt < 4; ++mt) {
    const int a0 = m0w + 16 * mt;
    const unsigned short* krow = sK + (a0 + l16) * SQ_STRIDE + 8 * q4;
    bh8 kf0 = *(const bh8*)(krow);
    bh8 kf1 = *(const bh8*)(krow + 32);
    f32x4 ctxa[4];
#pragma unroll
    for (int dt = 0; dt < 4; ++dt) ctxa[dt] = (f32x4){0.f, 0.f, 0.f, 0.f};
    float rs = 0.f;  // row-sum for row a = a0+l16 (lane-local partial)

#pragma unroll 1
    for (int ct = 0; ct < 8; ++ct) {
      // Swapped QK^T: s[r] = S[c0+4*q4+r][a0+l16]
      int ph0[2], ph1[2];
#pragma unroll
      for (int h = 0; h < 2; ++h) {
        const int c0 = 32 * ct + 16 * h;
        const unsigned short* qrow = sQ + (c0 + l16) * SQ_STRIDE + 8 * q4;
        bh8 qf0 = *(const bh8*)(qrow);
        bh8 qf1 = *(const bh8*)(qrow + 32);
        f32x4 s = {0.f, 0.f, 0.f, 0.f};
        s = MFMA(qf0, kf0, s);
        s = MFMA(qf1, kf1, s);
        float v0 = fmaxf(s[0] * 0.125f, 0.f);
        float v1 = fmaxf(s[1] * 0.125f, 0.f);
        float v2 = fmaxf(s[2] * 0.125f, 0.f);
        float v3 = fmaxf(s[3] * 0.125f, 0.f);
        rs += (v0 + v1) + (v2 + v3);
        if (h == 0) { ph0[0] = pkbf(v0, v1); ph0[1] = pkbf(v2, v3); }
        else        { ph1[0] = pkbf(v0, v1); ph1[1] = pkbf(v2, v3); }
      }
      // Build PV B-fragment in-register (no LDS, no barrier):
      // pf element s (k = 8*q4+s) = P[c-rel = 8*q4+s][a = l16].
      union { int d[4]; bh8 v; } pfu;
#pragma unroll
      for (int j = 0; j < 4; ++j) {
        const int srcl = (j < 2) ? srcA : srcB;
        int t0, t1;
        if ((j & 1) == 0) { t0 = __shfl(ph0[0], srcl); t1 = __shfl(ph1[0], srcl); }
        else              { t0 = __shfl(ph0[1], srcl); t1 = __shfl(ph1[1], srcl); }
        pfu.d[j] = hsel ? t1 : t0;
      }
#pragma unroll
      for (int dt = 0; dt < 4; ++dt) {
        bh8 vf = *(const bh8*)(sVt + (16 * dt + l16) * SVT_STRIDE + 32 * ct + 8 * q4);
        ctxa[dt] = MFMA(vf, pfu.v, ctxa[dt]);  // ctx^T[d][a]
      }
    }

    // denom = sum_c relu + M*1e-12 (reference adds 1e-12 inside the sum)
    rs += __shfl_xor(rs, 16);
    rs += __shfl_xor(rs, 32);
    const float inv = 1.f / (rs + 2.56e-10f);

    // ctx^T -> stg (row = a-rel = l16, col = d), then read back as R0 did.
#pragma unroll
    for (int dt = 0; dt < 4; ++dt)
#pragma unroll
      for (int r = 0; r < 4; ++r)
        stg[l16 * SC_STRIDE + 16 * dt + 4 * q4 + r] = f2bf(ctxa[dt][r] * inv);
    __syncthreads();  // insurance: ctx stage write -> read
    const unsigned short* crow = stg + l16 * SC_STRIDE + 8 * q4;
    bh8 cf0 = *(const bh8*)(crow);
    bh8 cf1 = *(const bh8*)(crow + 32);

    float yv[4][4];
    float s1[4] = {0.f, 0.f, 0.f, 0.f};
    float s2[4] = {0.f, 0.f, 0.f, 0.f};
#pragma unroll
    for (int nt = 0; nt < 4; ++nt) {
      f32x4 o = {0.f, 0.f, 0.f, 0.f};
      o = MFMA(cf0, wo[nt][0], o);
      o = MFMA(cf1, wo[nt][1], o);
#pragma unroll
      for (int r = 0; r < 4; ++r) {
        float y = o[r] + bof[nt] +
                  g_loadf<FP32>(Xv, xoff + (size_t)(a0 + 4 * q4 + r) * 64 + 16 * nt + l16);
        yv[nt][r] = y;
        s1[r] += y;
        s2[r] += y * y;
      }
    }
#pragma unroll
    for (int r = 0; r < 4; ++r) {
      s1[r] += __shfl_xor(s1[r], 1);
      s1[r] += __shfl_xor(s1[r], 2);
      s1[r] += __shfl_xor(s1[r], 4);
      s1[r] += __shfl_xor(s1[r], 8);
      s2[r] += __shfl_xor(s2[r], 1);
      s2[r] += __shfl_xor(s2[r], 2);
      s2[r] += __shfl_xor(s2[r], 4);
      s2[r] += __shfl_xor(s2[r], 8);
      const float mu   = s1[r] * 0.015625f;
      const float var  = s2[r] * 0.015625f - mu * mu;
      const float rstd = rsqrtf(var + 1e-5f);
      if constexpr (FP32) {
        float* Outf = (float*)Outv;
#pragma unroll
        for (int nt = 0; nt < 4; ++nt)
          Outf[xoff + (size_t)(a0 + 4 * q4 + r) * 64 + 16 * nt + l16] =
              (yv[nt][r] - mu) * rstd * gf[nt] + lbf[nt];
      } else {
#pragma unroll
        for (int nt = 0; nt < 4; ++nt)
          stg[(4 * q4 + r) * SY_STRIDE + 16 * nt + l16] =
              f2bf((yv[nt][r] - mu) * rstd * gf[nt] + lbf[nt]);
      }
    }
    if constexpr (!FP32) {
      __syncthreads();  // insurance: y stage write -> read
      const int row = lane >> 2, seg = lane & 3;
      const unsigned short* yr = stg + row * SY_STRIDE + seg * 8;
      uint4 u0 = *(const uint4*)(yr);
      uint4 u1 = *(const uint4*)(yr + 32);
      unsigned short* orow =
          (unsigned short*)Outv + xoff + (size_t)(a0 + row) * 64 + seg * 8;
      *(uint4*)(orow)      = u0;
      *(uint4*)(orow + 32) = u1;
    }
  }
}

extern "C" void kernel_launch(void* const* d_in, const int* in_sizes, int n_in,
                              void* d_out, int out_size, void* d_ws, size_t ws_size,
                              hipStream_t stream) {
  (void)n_in; (void)d_ws; (void)ws_size; (void)out_size;
  const void* X  = d_in[1];   // structure_matrix (d_in[0]=hidden_states unused)
  const void* Wq = d_in[2];  const void* bq = d_in[3];
  const void* Wk = d_in[4];  const void* bk = d_in[5];
  const void* Wv = d_in[6];  const void* bv = d_in[7];
  const void* Wo = d_in[8];  const void* bo = d_in[9];
  const void* lg = d_in[10]; const void* lb = d_in[11];

  // Host-side dtype dispatch: structure_matrix has 4*256*256*64 = 16777216
  // elements. If in_sizes[1] is a byte count it identifies the dtype and we
  // launch ONE kernel; any other value -> launch both (device sniff makes
  // the wrong one exit early, as before).
  const long long NELT = 16777216LL;
  const long long sz1  = (long long)in_sizes[1];
  bool want_bf16 = true, want_f32 = true;
  if (sz1 == NELT * 2) want_f32 = false;        // bf16 bytes
  else if (sz1 == NELT * 4) want_bf16 = false;  // fp32 bytes

  auto k0 = pairattn<0>;  // bf16 inputs/outputs
  auto k1 = pairattn<1>;  // fp32 inputs/outputs
  if (want_bf16) {
    hipFuncSetAttribute((const void*)k0, hipFuncAttributeMaxDynamicSharedMemorySize, LDS_BYTES);
    k0<<<1024, 256, LDS_BYTES, stream>>>(X, Wq, bq, Wk, bk, Wv, bv, Wo, bo, lg, lb, d_out);
  }
  if (want_f32) {
    hipFuncSetAttribute((const void*)k1, hipFuncAttributeMaxDynamicSharedMemorySize, LDS_BYTES);
    k1<<<1024, 256, LDS_BYTES, stream>>>(X, Wq, bq, Wk, bk, Wv, bv, Wo, bo, lg, lb, d_out);
  }
}